// Round 1
// 2972.780 us; speedup vs baseline: 1.1991x; 1.1991x over previous
//
#include <hip/hip_runtime.h>
#include <hip/hip_bf16.h>
#include <stdint.h>

// ---------------- model constants ----------------
#define EMB    1024
#define NH     16
#define HD     64
#define SEQ    1024
#define NBATCH 4
#define NTOK   4096        // NBATCH*SEQ
#define VOCAB  32000
#define NL     3
#define FFD    4096
#define LN_EPS 1e-5f

typedef __attribute__((ext_vector_type(8))) __bf16 bf16x8;
typedef __attribute__((ext_vector_type(4))) float  f32x4;

__device__ inline unsigned short f2b(float f) {
  __hip_bfloat16 h = __float2bfloat16(f);          // RNE
  return *reinterpret_cast<unsigned short*>(&h);
}
__device__ inline float b2f(unsigned short u) {
  unsigned x = ((unsigned)u) << 16;
  return __uint_as_float(x);
}

// async global->LDS, 16 bytes per lane. LDS dest = wave-uniform base + lane*16.
__device__ inline void gload16(const void* g, void* l) {
  __builtin_amdgcn_global_load_lds(
      (const __attribute__((address_space(1))) unsigned int*)g,
      (__attribute__((address_space(3))) unsigned int*)l, 16, 0, 0);
}

// ---------------- generic batched bf16 GEMM: C = A[M,K] * Bt[N,K]^T ----------------
// m97 structure: 128x128 tile, 256 threads = 4 waves (2x2), 4x4 acc of 16x16x32 MFMA,
// K-step 32, global_load_lds width=16 into LINEAR [128][32] LDS (required: gload_lds
// writes wave-base + lane*16 contiguously; padding would misplace lanes — m104/m108).
// OOB M/N rows: clamp the GLOBAL source address (no fault); garbage only reaches
// C rows/cols that the store guard masks (MFMA col n depends only on B row n).
// flags: 1 = relu, 2 = causal mask (col>row -> -inf, LOCAL row/col, per-batch)
__global__ __launch_bounds__(256) void gemm_bt(
    const unsigned short* __restrict__ A,
    const unsigned short* __restrict__ Bt,
    float* __restrict__ Cf,             // fp32 out (or null)
    unsigned short* __restrict__ Cb,    // bf16 out (or null)
    const float* __restrict__ resid,    // fp32 residual, same layout as C (or null)
    const float* __restrict__ bias,     // per-n fp32 bias (or null)
    int M, int N, int K,
    int lda, int ldb, int ldc,
    int nb2, long sa1, long sa2, long sb1, long sb2, long sc1, long sc2,
    float scale, int flags)
{
  __shared__ __align__(16) unsigned short As[128 * 32];
  __shared__ __align__(16) unsigned short Bs[128 * 32];

  int z  = blockIdx.z;
  int i1 = z / nb2, i2 = z - i1 * nb2;
  long aoff = (long)i1 * sa1 + (long)i2 * sa2;
  long boff = (long)i1 * sb1 + (long)i2 * sb2;
  long coff = (long)i1 * sc1 + (long)i2 * sc2;

  // XCD-aware bijective tile swizzle (T1): only for single-slice grids where
  // flat id % 8 == real XCD. Consecutive tiles -> same XCD L2 (m192: +10% @HBM-bound).
  int flat = blockIdx.y * gridDim.x + blockIdx.x;
  int nwg  = gridDim.x * gridDim.y;
  if (gridDim.z == 1 && nwg > 8) {
    int q = nwg >> 3, rq = nwg & 7;
    int xcd = flat & 7, idx = flat >> 3;
    flat = (xcd < rq ? xcd * (q + 1) : rq * (q + 1) + (xcd - rq) * q) + idx;
  }
  int n0 = (flat % gridDim.x) * 128;
  int m0 = (flat / gridDim.x) * 128;

  int t    = threadIdx.x;
  int wave = t >> 6, lane = t & 63;
  int wm   = wave >> 1, wn = wave & 1;
  int quad = lane >> 4, l16 = lane & 15;

  // fully-masked causal tile: all outputs -inf, skip the K loop entirely
  if ((flags & 2) && n0 >= m0 + 128) {
    unsigned short ninf = f2b(-__builtin_inff());
#pragma unroll
    for (int i = 0; i < 4; ++i)
#pragma unroll
      for (int j = 0; j < 4; ++j)
#pragma unroll
        for (int r = 0; r < 4; ++r) {
          int m = m0 + wm * 64 + i * 16 + quad * 4 + r;
          int n = n0 + wn * 64 + j * 16 + l16;
          if (m < M && n < N) Cb[coff + (long)m * ldc + n] = ninf;
        }
    return;
  }

  f32x4 acc[4][4];
#pragma unroll
  for (int i = 0; i < 4; ++i)
#pragma unroll
    for (int j = 0; j < 4; ++j)
      acc[i][j] = (f32x4){0.f, 0.f, 0.f, 0.f};

  // staging geometry: wave w, round r covers LDS rows r*64 + w*16 .. +15;
  // lane covers row (lane>>2), 16B chunk (lane&3) of the 64B row.
  const unsigned short* Ag = A + aoff;
  const unsigned short* Bg = Bt + boff;
  int srow = wave * 16 + (lane >> 2);   // 0..63 (+64 on round 1)
  int kcol = (lane & 3) * 8;            // element offset of this lane's 16B

  for (int kt = 0; kt < K; kt += 32) {
    __syncthreads();                    // prior ds_reads done before overwrite
#pragma unroll
    for (int r = 0; r < 2; ++r) {
      int gm = m0 + r * 64 + srow; if (gm >= M) gm = M - 1;   // clamp, see header
      int gn = n0 + r * 64 + srow; if (gn >= N) gn = N - 1;
      gload16(Ag + (long)gm * lda + kt + kcol, As + r * 2048 + wave * 512);
      gload16(Bg + (long)gn * ldb + kt + kcol, Bs + r * 2048 + wave * 512);
    }
    __syncthreads();                    // compiler drains vmcnt(0) before barrier

    bf16x8 af[4], bv[4];
#pragma unroll
    for (int i = 0; i < 4; ++i)        // A frag: m = lane&15, k = quad*8+j
      af[i] = *(const bf16x8*)&As[(wm * 64 + i * 16 + l16) * 32 + quad * 8];
#pragma unroll
    for (int j = 0; j < 4; ++j)        // B frag: n = lane&15, k = quad*8+j
      bv[j] = *(const bf16x8*)&Bs[(wn * 64 + j * 16 + l16) * 32 + quad * 8];
#pragma unroll
    for (int i = 0; i < 4; ++i)
#pragma unroll
      for (int j = 0; j < 4; ++j)
        acc[i][j] = __builtin_amdgcn_mfma_f32_16x16x32_bf16(af[i], bv[j], acc[i][j], 0, 0, 0);
  }

  // epilogue: C/D layout col=lane&15, row=quad*4+reg (m89/m91 verified)
#pragma unroll
  for (int i = 0; i < 4; ++i) {
#pragma unroll
    for (int j = 0; j < 4; ++j) {
#pragma unroll
      for (int r = 0; r < 4; ++r) {
        int m = m0 + wm * 64 + i * 16 + quad * 4 + r;
        int n = n0 + wn * 64 + j * 16 + l16;
        if (m < M && n < N) {
          float v = acc[i][j][r] * scale;
          if ((flags & 2) && n > m) v = -__builtin_inff();
          if (bias)  v += bias[n];
          if (resid) v += resid[coff + (long)m * ldc + n];
          if (flags & 1) v = fmaxf(v, 0.f);
          long off = coff + (long)m * ldc + n;
          if (Cb) Cb[off] = f2b(v);
          else    Cf[off] = v;
        }
      }
    }
  }
}

// ---------------- tiled transpose fp32 -> bf16: out[c*R + r] = in[r*ld_in + c] ----------------
__global__ void transpose_fb(const float* __restrict__ in, unsigned short* __restrict__ out,
                             int R, int C, int ld_in,
                             int nb2, long is1, long is2, long os1, long os2)
{
  __shared__ float tile[32][33];
  int z = blockIdx.z;
  int i1 = z / nb2, i2 = z - i1 * nb2;
  const float* ip = in + (long)i1 * is1 + (long)i2 * is2;
  unsigned short* op = out + (long)i1 * os1 + (long)i2 * os2;
  int c0 = blockIdx.x * 32, r0 = blockIdx.y * 32;
  int tx = threadIdx.x, ty = threadIdx.y;  // (32,8)
#pragma unroll
  for (int i = 0; i < 32; i += 8) {
    int r = r0 + ty + i, c = c0 + tx;
    if (r < R && c < C) tile[ty + i][tx] = ip[(long)r * ld_in + c];
  }
  __syncthreads();
#pragma unroll
  for (int i = 0; i < 32; i += 8) {
    int c = c0 + ty + i, r = r0 + tx;
    if (r < R && c < C) op[(long)c * R + r] = f2b(tile[tx][ty + i]);
  }
}

// same but bf16 -> bf16 (for v^T)
__global__ void transpose_bb(const unsigned short* __restrict__ in, unsigned short* __restrict__ out,
                             int R, int C, int ld_in,
                             int nb2, long is1, long is2, long os1, long os2)
{
  __shared__ unsigned short tile[32][33];
  int z = blockIdx.z;
  int i1 = z / nb2, i2 = z - i1 * nb2;
  const unsigned short* ip = in + (long)i1 * is1 + (long)i2 * is2;
  unsigned short* op = out + (long)i1 * os1 + (long)i2 * os2;
  int c0 = blockIdx.x * 32, r0 = blockIdx.y * 32;
  int tx = threadIdx.x, ty = threadIdx.y;
#pragma unroll
  for (int i = 0; i < 32; i += 8) {
    int r = r0 + ty + i, c = c0 + tx;
    if (r < R && c < C) tile[ty + i][tx] = ip[(long)r * ld_in + c];
  }
  __syncthreads();
#pragma unroll
  for (int i = 0; i < 32; i += 8) {
    int c = c0 + ty + i, r = r0 + tx;
    if (r < R && c < C) op[(long)c * R + r] = tile[tx][ty + i];
  }
}

// ---------------- embedding: x[row] = tok_emb[ids[row]] + pos_emb[row % SEQ] ----------------
__global__ void embed_k(const int* __restrict__ ids, const float* __restrict__ tok,
                        const float* __restrict__ pos, float* __restrict__ x)
{
  int row = blockIdx.x;
  int tp  = row & (SEQ - 1);
  int id  = ids[row];
  const float* tr = tok + (long)id * EMB;
  const float* pr = pos + (long)tp * EMB;
  float* xr = x + (long)row * EMB;
  for (int i = threadIdx.x; i < EMB; i += 256) xr[i] = tr[i] + pr[i];
}

// ---------------- layernorm (fp32 in, bf16 out), one block per row ----------------
__global__ void ln_k(const float* __restrict__ x, const float* __restrict__ g,
                     const float* __restrict__ b, unsigned short* __restrict__ h)
{
  __shared__ float sm[8];
  int row = blockIdx.x;
  const float* xr = x + (long)row * EMB;
  float v[4]; float s = 0.f, s2 = 0.f;
#pragma unroll
  for (int i = 0; i < 4; ++i) {
    v[i] = xr[threadIdx.x + i * 256];
    s += v[i]; s2 += v[i] * v[i];
  }
  for (int off = 32; off > 0; off >>= 1) {
    s  += __shfl_down(s,  off, 64);
    s2 += __shfl_down(s2, off, 64);
  }
  int wave = threadIdx.x >> 6, lane = threadIdx.x & 63;
  if (lane == 0) { sm[wave * 2] = s; sm[wave * 2 + 1] = s2; }
  __syncthreads();
  s  = sm[0] + sm[2] + sm[4] + sm[6];
  s2 = sm[1] + sm[3] + sm[5] + sm[7];
  float mu  = s * (1.f / EMB);
  float var = s2 * (1.f / EMB) - mu * mu;
  float inv = rsqrtf(var + LN_EPS);
  unsigned short* hr = h + (long)row * EMB;
#pragma unroll
  for (int i = 0; i < 4; ++i) {
    int e = threadIdx.x + i * 256;
    hr[e] = f2b((v[i] - mu) * inv * g[e] + b[e]);
  }
}

// ---------------- row softmax, in-place on bf16 scores (one block per row of 1024) -------------
__global__ void softmax_k(unsigned short* __restrict__ S)
{
  __shared__ float sm[4];
  long row = blockIdx.x;
  unsigned short* r = S + row * 1024;
  float v[4]; float mx = -__builtin_inff();
#pragma unroll
  for (int i = 0; i < 4; ++i) { v[i] = b2f(r[threadIdx.x + i * 256]); mx = fmaxf(mx, v[i]); }
  for (int off = 32; off > 0; off >>= 1) mx = fmaxf(mx, __shfl_down(mx, off, 64));
  int wave = threadIdx.x >> 6, lane = threadIdx.x & 63;
  if (lane == 0) sm[wave] = mx;
  __syncthreads();
  mx = fmaxf(fmaxf(sm[0], sm[1]), fmaxf(sm[2], sm[3]));
  __syncthreads();
  float e[4]; float s = 0.f;
#pragma unroll
  for (int i = 0; i < 4; ++i) { e[i] = __expf(v[i] - mx); s += e[i]; }   // exp(-inf)=0
  for (int off = 32; off > 0; off >>= 1) s += __shfl_down(s, off, 64);
  if (lane == 0) sm[wave] = s;
  __syncthreads();
  s = sm[0] + sm[1] + sm[2] + sm[3];
  float inv = 1.f / s;
#pragma unroll
  for (int i = 0; i < 4; ++i) r[threadIdx.x + i * 256] = f2b(e[i] * inv);
}

// ---------------- per-row loss: lse(logits_row) - logits_row[tgt] (online logsumexp) ----------
__global__ void loss_rows_k(const float* __restrict__ logits, const int* __restrict__ tgt,
                            float* __restrict__ rowloss)
{
  __shared__ float smm[4], sms[4];
  int row = blockIdx.x;
  const float* lr = logits + (long)row * VOCAB;
  float m = -__builtin_inff(), s = 0.f;
  for (int i = threadIdx.x; i < VOCAB; i += 256) {    // 125 elems/thread, all threads active
    float x = lr[i];
    float nm = fmaxf(m, x);
    s = s * __expf(m - nm) + __expf(x - nm);
    m = nm;
  }
  for (int off = 32; off > 0; off >>= 1) {
    float om = __shfl_down(m, off, 64);
    float os = __shfl_down(s, off, 64);
    float nm = fmaxf(m, om);
    s = s * __expf(m - nm) + os * __expf(om - nm);
    m = nm;
  }
  int wave = threadIdx.x >> 6, lane = threadIdx.x & 63;
  if (lane == 0) { smm[wave] = m; sms[wave] = s; }
  __syncthreads();
  if (threadIdx.x == 0) {
    float M0 = fmaxf(fmaxf(smm[0], smm[1]), fmaxf(smm[2], smm[3]));
    float S0 = 0.f;
    for (int w = 0; w < 4; ++w) S0 += sms[w] * __expf(smm[w] - M0);
    rowloss[row] = M0 + logf(S0) - lr[tgt[row]];
  }
}

__global__ void loss_reduce_k(const float* __restrict__ rowloss, float* __restrict__ out)
{
  __shared__ float sm[4];
  float s = 0.f;
  for (int i = threadIdx.x; i < NTOK; i += 256) s += rowloss[i];
  for (int off = 32; off > 0; off >>= 1) s += __shfl_down(s, off, 64);
  int wave = threadIdx.x >> 6, lane = threadIdx.x & 63;
  if (lane == 0) sm[wave] = s;
  __syncthreads();
  if (threadIdx.x == 0) out[0] = (sm[0] + sm[1] + sm[2] + sm[3]) * (1.f / NTOK);
}

// ============================== host orchestration ==============================
extern "C" void kernel_launch(void* const* d_in, const int* in_sizes, int n_in,
                              void* d_out, int out_size, void* d_ws, size_t ws_size,
                              hipStream_t stream)
{
  const int*   ids  = (const int*)d_in[0];
  const int*   tgt  = (const int*)d_in[1];
  const float* tok  = (const float*)d_in[2];
  const float* pos  = (const float*)d_in[3];
  const float* wq   = (const float*)d_in[4];
  const float* wk   = (const float*)d_in[5];
  const float* wv   = (const float*)d_in[6];
  const float* wo   = (const float*)d_in[7];
  const float* bo   = (const float*)d_in[8];
  const float* ln1g = (const float*)d_in[9];
  const float* ln1b = (const float*)d_in[10];
  const float* w1   = (const float*)d_in[11];
  const float* b1   = (const float*)d_in[12];
  const float* w2   = (const float*)d_in[13];
  const float* b2   = (const float*)d_in[14];
  const float* lnfg = (const float*)d_in[15];
  const float* lnfb = (const float*)d_in[16];
  const float* lmw  = (const float*)d_in[17];
  const float* lmb  = (const float*)d_in[18];

  float* logits = (float*)d_out;
  float* loss   = logits + (long)NTOK * VOCAB;

  // workspace carve-up (~380 MB)
  char* p = (char*)d_ws;
  auto alloc = [&](size_t bytes) { char* q = p; p += (bytes + 255) & ~(size_t)255; return q; };
  float*          x    = (float*)alloc((size_t)NTOK * EMB * 4);
  unsigned short* h    = (unsigned short*)alloc((size_t)NTOK * EMB * 2);
  unsigned short* qkv  = (unsigned short*)alloc((size_t)NTOK * 3 * EMB * 2);
  unsigned short* vT   = (unsigned short*)alloc((size_t)NBATCH * NH * HD * SEQ * 2);
  unsigned short* S    = (unsigned short*)alloc((size_t)NBATCH * NH * SEQ * SEQ * 2);
  unsigned short* o    = (unsigned short*)alloc((size_t)NTOK * EMB * 2);
  unsigned short* ff   = (unsigned short*)alloc((size_t)NTOK * FFD * 2);
  unsigned short* Wqkv = (unsigned short*)alloc((size_t)NL * 3 * EMB * EMB * 2);
  unsigned short* Wo   = (unsigned short*)alloc((size_t)NL * EMB * EMB * 2);
  unsigned short* W1   = (unsigned short*)alloc((size_t)NL * EMB * FFD * 2);
  unsigned short* W2   = (unsigned short*)alloc((size_t)NL * EMB * FFD * 2);
  unsigned short* LM   = (unsigned short*)alloc((size_t)VOCAB * EMB * 2);
  float*          rls  = (float*)alloc((size_t)NTOK * 4);

  dim3 tb(32, 8);
  const long LEE = (long)EMB * EMB;

  // ---- weight prep: transpose + cast to bf16 (re-done every call; ws is re-poisoned) ----
  for (int l = 0; l < NL; ++l) {
    // wq/wk/wv[l][h]: [EMB,HD] -> rows h*64+d of Wqkv_t (batched over 16 heads)
    transpose_fb<<<dim3(2, 32, 16), tb, 0, stream>>>(wq + (long)l * NH * EMB * HD,
        Wqkv + (long)l * 3 * LEE,            EMB, HD, HD, 16, 0, (long)EMB * HD, 0, (long)HD * EMB);
    transpose_fb<<<dim3(2, 32, 16), tb, 0, stream>>>(wk + (long)l * NH * EMB * HD,
        Wqkv + (long)l * 3 * LEE + LEE,      EMB, HD, HD, 16, 0, (long)EMB * HD, 0, (long)HD * EMB);
    transpose_fb<<<dim3(2, 32, 16), tb, 0, stream>>>(wv + (long)l * NH * EMB * HD,
        Wqkv + (long)l * 3 * LEE + 2 * LEE,  EMB, HD, HD, 16, 0, (long)EMB * HD, 0, (long)HD * EMB);
    transpose_fb<<<dim3(32, 32, 1), tb, 0, stream>>>(wo + l * LEE, Wo + l * LEE,
        EMB, EMB, EMB, 1, 0, 0, 0, 0);
    transpose_fb<<<dim3(128, 32, 1), tb, 0, stream>>>(w1 + (long)l * EMB * FFD, W1 + (long)l * EMB * FFD,
        EMB, FFD, FFD, 1, 0, 0, 0, 0);
    transpose_fb<<<dim3(32, 128, 1), tb, 0, stream>>>(w2 + (long)l * EMB * FFD, W2 + (long)l * EMB * FFD,
        FFD, EMB, EMB, 1, 0, 0, 0, 0);
  }
  transpose_fb<<<dim3(1000, 32, 1), tb, 0, stream>>>(lmw, LM, EMB, VOCAB, VOCAB, 1, 0, 0, 0, 0);

  // ---- embedding ----
  embed_k<<<NTOK, 256, 0, stream>>>(ids, tok, pos, x);

  // ---- transformer layers ----
  for (int l = 0; l < NL; ++l) {
    const float* g1  = ln1g + l * EMB;
    const float* bb1 = ln1b + l * EMB;

    ln_k<<<NTOK, 256, 0, stream>>>(x, g1, bb1, h);

    // fused QKV projection: [4096,1024] x [3072,1024]^T -> qkv [4096,3072] bf16
    gemm_bt<<<dim3(24, 32, 1), 256, 0, stream>>>(h, Wqkv + (long)l * 3 * LEE, nullptr, qkv,
        nullptr, nullptr, NTOK, 3 * EMB, EMB, EMB, EMB, 3 * EMB,
        1, 0, 0, 0, 0, 0, 0, 1.f, 0);

    // v^T per (b,h): [SEQ,HD] -> [HD,SEQ]
    transpose_bb<<<dim3(2, 32, NBATCH * NH), tb, 0, stream>>>(qkv + 2 * EMB, vT,
        SEQ, HD, 3 * EMB, NH, (long)SEQ * 3 * EMB, (long)HD, (long)NH * HD * SEQ, (long)HD * SEQ);

    // S = Q K^T * 1/32, causal -inf, bf16, batched over (b,h)
    gemm_bt<<<dim3(8, 8, NBATCH * NH), 256, 0, stream>>>(qkv, qkv + EMB, nullptr, S,
        nullptr, nullptr, SEQ, SEQ, HD, 3 * EMB, 3 * EMB, SEQ,
        NH, (long)SEQ * 3 * EMB, (long)HD, (long)SEQ * 3 * EMB, (long)HD,
        (long)NH * SEQ * SEQ, (long)SEQ * SEQ, 0.03125f, 2);

    softmax_k<<<NBATCH * NH * SEQ, 256, 0, stream>>>(S);

    // O = P V, batched; write as [b,t,h,d] (ldc=EMB, head offset 64)
    gemm_bt<<<dim3(1, 8, NBATCH * NH), 256, 0, stream>>>(S, vT, nullptr, o,
        nullptr, nullptr, SEQ, HD, SEQ, SEQ, SEQ, EMB,
        NH, (long)NH * SEQ * SEQ, (long)SEQ * SEQ, (long)NH * HD * SEQ, (long)HD * SEQ,
        (long)SEQ * EMB, (long)HD, 1.f, 0);

    // x = x + O Wo^T + bo  (fp32 residual, in-place)
    gemm_bt<<<dim3(8, 32, 1), 256, 0, stream>>>(o, Wo + l * LEE, x, nullptr,
        x, bo + l * EMB, NTOK, EMB, EMB, EMB, EMB, EMB,
        1, 0, 0, 0, 0, 0, 0, 1.f, 0);

    // second LN (reference reuses ln1 params)
    ln_k<<<NTOK, 256, 0, stream>>>(x, g1, bb1, h);

    // ff = relu(h W1^T + b1) -> bf16 [4096,4096]
    gemm_bt<<<dim3(32, 32, 1), 256, 0, stream>>>(h, W1 + (long)l * EMB * FFD, nullptr, ff,
        nullptr, b1 + l * FFD, NTOK, FFD, EMB, EMB, EMB, FFD,
        1, 0, 0, 0, 0, 0, 0, 1.f, 1);

    // x = x + ff W2^T + b2
    gemm_bt<<<dim3(8, 32, 1), 256, 0, stream>>>(ff, W2 + (long)l * EMB * FFD, x, nullptr,
        x, b2 + l * EMB, NTOK, EMB, FFD, FFD, FFD, EMB,
        1, 0, 0, 0, 0, 0, 0, 1.f, 0);
  }

  // ---- final LN + LM head ----
  ln_k<<<NTOK, 256, 0, stream>>>(x, lnfg, lnfb, h);
  gemm_bt<<<dim3(250, 32, 1), 256, 0, stream>>>(h, LM, logits, nullptr,
      nullptr, lmb, NTOK, VOCAB, EMB, EMB, EMB, VOCAB,
      1, 0, 0, 0, 0, 0, 0, 1.f, 0);

  // ---- loss ----
  loss_rows_k<<<NTOK, 256, 0, stream>>>(logits, tgt, rls);
  loss_reduce_k<<<1, 256, 0, stream>>>(rls, loss);
}